// Round 1
// baseline (26.944 us; speedup 1.0000x reference)
//
#include <hip/hip_runtime.h>
#include <math.h>

// Problem constants (from reference)
#define NB   512    // N_BASIS
#define DXN  100    // DX quadrature points
#define MROW 128    // M
#define TC   130    // theta columns (M+2)
#define G    8      // rows per block
#define BT   512    // threads per block

__device__ __forceinline__ float Tval(int t) {
    return -5.0f + (10.0f / 99.0f) * (float)t;
}

// Kernel 1: materialize K[128][100] and phi1T[100][512] (transposed phi1) into ws.
__global__ __launch_bounds__(256) void precompute_kernel(
    const float* __restrict__ mu, const float* __restrict__ sigma,
    float* __restrict__ Kmat, float* __restrict__ phi1T)
{
    int idx = blockIdx.x * 256 + threadIdx.x;
    if (idx < MROW * DXN) {
        int j = idx / DXN;
        int t = idx - j * DXN;
        float d = (float)j * (1.0f / 127.0f) - Tval(t);
        // exp(-0.5*d*d/0.01) = exp(-50*d*d)
        Kmat[idx] = expf(-50.0f * d * d);
    } else if (idx < MROW * DXN + DXN * NB) {
        int rem = idx - MROW * DXN;
        int t = rem / NB;
        int n = rem - t * NB;
        float inv_s = 1.0f / sigma[n];
        float u = (mu[n] - Tval(t)) * inv_s;
        phi1T[rem] = 0.3989422804014327f * expf(-0.5f * u * u) * inv_s;
    }
}

// Kernel 2: fused f -> exp_terms -> Z -> density -> out for G rows per block.
__global__ __launch_bounds__(BT) void fused_kernel(
    const float* __restrict__ theta,
    const float* __restrict__ Kmat,
    const float* __restrict__ phi1T,
    float* __restrict__ out, int Bn)
{
    __shared__ float s_alpha[G][MROW];
    __shared__ float s_th0[G], s_th1[G];
    __shared__ float s_muc[G], s_negth1[G];
    __shared__ float s_dw[DXN][G];    // exp_terms * w, transposed for b128 broadcast
    __shared__ float s_invZ[G];

    const int tid = threadIdx.x;
    const int b0 = blockIdx.x * G;

    // Phase A: load G theta rows (130 floats each) into LDS
    for (int i = tid; i < G * TC; i += BT) {
        int r = i / TC;
        int c = i - r * TC;
        int br = b0 + r; if (br >= Bn) br = Bn - 1;   // clamp (Bn multiple of G in practice)
        float v = theta[br * TC + c];
        if (c >= 2)      s_alpha[r][c - 2] = v;
        else if (c == 0) s_th0[r] = v;
        else             s_th1[r] = v;
    }
    __syncthreads();
    if (tid < G) {
        float th1 = s_th1[tid];                 // <= -0.5
        s_muc[tid]    = s_th0[tid] * (-0.5f / th1);   // mu_c = theta0 * sigma_sq
        s_negth1[tid] = -th1;                   // quad = 0.5*d^2/ssq = -th1 * d^2
    }
    __syncthreads();

    // Phase B: dw[t][r] = max(1 + f - quad, 1e-8) * w[t]
    // K(t) is numerically zero unless T[t] is within ~0.77 of [0,1] -> t in [42,67].
    for (int task = tid; task < G * DXN; task += BT) {
        int r = task / DXN;
        int t = task - r * DXN;
        float f = 0.0f;
        if (t >= 42 && t <= 67) {
            float f0 = 0.f, f1 = 0.f, f2 = 0.f, f3 = 0.f;
            const float* Kc = Kmat + t;
            const float* al = s_alpha[r];
            #pragma unroll 4
            for (int j = 0; j < MROW; j += 4) {
                f0 += al[j + 0] * Kc[(j + 0) * DXN];
                f1 += al[j + 1] * Kc[(j + 1) * DXN];
                f2 += al[j + 2] * Kc[(j + 2) * DXN];
                f3 += al[j + 3] * Kc[(j + 3) * DXN];
            }
            f = (f0 + f1) + (f2 + f3);
        }
        float dmu = s_muc[r] - Tval(t);
        float quad = s_negth1[r] * dmu * dmu;
        float e = fmaxf(1.0f + f - quad, 1e-8f);
        float w = (10.0f / 99.0f);
        if (t == 0 || t == DXN - 1) w *= 0.5f;
        s_dw[t][r] = e * w;
    }
    __syncthreads();

    // Phase C: Z per row -> invZ
    if (tid < G) {
        float z = 0.0f;
        for (int t = 0; t < DXN; ++t) z += s_dw[t][tid];
        s_invZ[tid] = 1.0f / z;
    }
    __syncthreads();

    // Phase D: out[b0+r][n] = (sum_t dw[t][r] * phi1T[t][n]) * invZ[r]
    float acc[G];
    #pragma unroll
    for (int r = 0; r < G; ++r) acc[r] = 0.0f;
    const int n = tid;   // 512 threads == 512 basis columns
    for (int t = 0; t < DXN; ++t) {
        float p = phi1T[t * NB + n];
        #pragma unroll
        for (int r = 0; r < G; ++r) acc[r] = fmaf(s_dw[t][r], p, acc[r]);
    }
    #pragma unroll
    for (int r = 0; r < G; ++r) {
        int br = b0 + r;
        if (br < Bn) out[br * NB + n] = acc[r] * s_invZ[r];
    }
}

extern "C" void kernel_launch(void* const* d_in, const int* in_sizes, int n_in,
                              void* d_out, int out_size, void* d_ws, size_t ws_size,
                              hipStream_t stream) {
    const float* theta = (const float*)d_in[0];
    const float* mu    = (const float*)d_in[1];
    const float* sigma = (const float*)d_in[2];
    float* outp  = (float*)d_out;
    float* Kmat  = (float*)d_ws;                 // 12800 floats
    float* phi1T = Kmat + MROW * DXN;            // 51200 floats (total 256 KB << ws)

    int Bn = in_sizes[0] / TC;                   // 4096
    int total = MROW * DXN + DXN * NB;           // 64000 elements to precompute
    precompute_kernel<<<(total + 255) / 256, 256, 0, stream>>>(mu, sigma, Kmat, phi1T);

    int grid = (Bn + G - 1) / G;                 // 512 blocks
    fused_kernel<<<grid, BT, 0, stream>>>(theta, Kmat, phi1T, outp, Bn);
}

// Round 2
// 19.411 us; speedup vs baseline: 1.3881x; 1.3881x over previous
//
#include <hip/hip_runtime.h>
#include <math.h>

// Problem constants (from reference)
#define NB   512    // N_BASIS
#define DXN  100    // DX quadrature points
#define MROW 128    // M
#define TC   130    // theta columns (M+2)
#define G    16     // rows per block
#define BT   512    // threads per block

#define T0f   (-5.0f)
#define Hf    (10.0f / 99.0f)
#define LOG2E 1.4426950408889634f
#define WLO   42    // t-window where K != 0 (|T - [0,1]| < 0.77)
#define WHI   67
#define WN    (WHI - WLO + 1)   // 26

__device__ __forceinline__ float Tval(int t) { return T0f + Hf * (float)t; }

// Single fused kernel: theta -> f -> exp_terms -> Z -> density -> out,
// with K and phi1 computed on the fly via additive log2-exponent recurrences
// (a_{k+1} = a_k + b_k; b_{k+1} = b_k + c; e = exp2(a) -> v_exp_f32).
__global__ __launch_bounds__(BT) void fused_kernel(
    const float* __restrict__ theta,
    const float* __restrict__ mu,
    const float* __restrict__ sigma,
    float* __restrict__ out, int Bn)
{
    __shared__ float  s_alpha[G][MROW];     // 8 KB
    __shared__ float  s_th0[G], s_th1[G];
    __shared__ float  s_muc[G], s_negth1[G];
    __shared__ float  s_f[G][WN];           // 1.7 KB
    __shared__ float4 s_dw4[DXN][G / 4];    // dw[t][r], r-minor, 6.4 KB
    __shared__ float  s_invZ[G];

    const int tid = threadIdx.x;
    const int b0  = blockIdx.x * G;
    float* s_dw = (float*)s_dw4;            // s_dw[t*G + r]

    // Issue per-thread phi parameters early (latency overlaps theta staging).
    const float mun = mu[tid];
    const float sg  = sigma[tid];

    // ---- Phase A: stage G theta rows into LDS ----
    for (int i = tid; i < G * TC; i += BT) {
        int r = i / TC, c = i - r * TC;
        int br = b0 + r; if (br >= Bn) br = Bn - 1;
        float v = theta[br * TC + c];
        if (c >= 2)      s_alpha[r][c - 2] = v;
        else if (c == 0) s_th0[r] = v;
        else             s_th1[r] = v;
    }
    __syncthreads();

    // ---- Phase B0: per-row scalars ----
    if (tid < G) {
        float th1 = s_th1[tid];               // <= -0.5
        s_muc[tid]    = s_th0[tid] * (-0.5f / th1);
        s_negth1[tid] = -th1;                 // quad = -th1 * (mu_c - T)^2
    }
    // ---- Phase B1: f(r,t) for the K-active window, 416 threads ----
    if (tid < G * WN) {
        int r  = tid / WN;
        int t  = WLO + (tid - r * WN);
        float T = Tval(t);
        // exp(-50 d^2) = exp2(-50*log2e*d^2), d_j = j/127 - T; additive recurrence in j
        const float C2 = 50.0f * LOG2E;
        const float dj = 1.0f / 127.0f;
        float d0 = -T;                                 // j = 0
        float a  = -C2 * d0 * d0;
        float bb = -C2 * dj * (2.0f * d0 + dj);
        const float cc = -2.0f * C2 * dj * dj;
        const float* al = s_alpha[r];
        float f = 0.0f;
        for (int jc = 0; jc < MROW / 4; ++jc) {
            float4 av = *(const float4*)&al[4 * jc];   // ds_read_b128
            f += av.x * __builtin_amdgcn_exp2f(a); a += bb; bb += cc;
            f += av.y * __builtin_amdgcn_exp2f(a); a += bb; bb += cc;
            f += av.z * __builtin_amdgcn_exp2f(a); a += bb; bb += cc;
            f += av.w * __builtin_amdgcn_exp2f(a); a += bb; bb += cc;
        }
        s_f[r][t - WLO] = f;
    }
    __syncthreads();

    // ---- Phase B2: dw[t][r] = max(1 + f - quad, 1e-8) * w[t]  (r-minor writes) ----
    for (int task = tid; task < G * DXN; task += BT) {
        int t = task >> 4;              // G == 16
        int r = task & (G - 1);
        float f = (t >= WLO && t <= WHI) ? s_f[r][t - WLO] : 0.0f;
        float dmu  = s_muc[r] - Tval(t);
        float quad = s_negth1[r] * dmu * dmu;
        float e = fmaxf(1.0f + f - quad, 1e-8f);
        float w = Hf; if (t == 0 || t == DXN - 1) w *= 0.5f;
        s_dw[t * G + r] = e * w;
    }
    __syncthreads();

    // ---- Phase C: Z per row (16 threads; overlaps Phase D start of other waves) ----
    if (tid < G) {
        float z = 0.0f;
        for (int t = 0; t < DXN; ++t) z += s_dw[t * G + tid];
        s_invZ[tid] = 1.0f / z;
    }

    // ---- Phase D: acc[r] = sum_t dw[t][r] * exp(-0.5 u_t^2), u_t = (mu_n - T_t)/sigma_n
    const float inv_s = 1.0f / sg;
    const float dlt = Hf * inv_s;
    const float u0  = (mun - T0f) * inv_s;
    const float Lh  = 0.5f * LOG2E;
    float a  = -Lh * u0 * u0;
    float bb = Lh * dlt * (2.0f * u0 - dlt);
    const float cc = -2.0f * Lh * dlt * dlt;

    float acc[G];
    #pragma unroll
    for (int r = 0; r < G; ++r) acc[r] = 0.0f;

    for (int t = 0; t < DXN; ++t) {
        float p = __builtin_amdgcn_exp2f(a);
        a += bb; bb += cc;
        float4 d0 = s_dw4[t][0];   // wave-uniform broadcast b128 reads
        float4 d1 = s_dw4[t][1];
        float4 d2 = s_dw4[t][2];
        float4 d3 = s_dw4[t][3];
        acc[ 0] = fmaf(d0.x, p, acc[ 0]);
        acc[ 1] = fmaf(d0.y, p, acc[ 1]);
        acc[ 2] = fmaf(d0.z, p, acc[ 2]);
        acc[ 3] = fmaf(d0.w, p, acc[ 3]);
        acc[ 4] = fmaf(d1.x, p, acc[ 4]);
        acc[ 5] = fmaf(d1.y, p, acc[ 5]);
        acc[ 6] = fmaf(d1.z, p, acc[ 6]);
        acc[ 7] = fmaf(d1.w, p, acc[ 7]);
        acc[ 8] = fmaf(d2.x, p, acc[ 8]);
        acc[ 9] = fmaf(d2.y, p, acc[ 9]);
        acc[10] = fmaf(d2.z, p, acc[10]);
        acc[11] = fmaf(d2.w, p, acc[11]);
        acc[12] = fmaf(d3.x, p, acc[12]);
        acc[13] = fmaf(d3.y, p, acc[13]);
        acc[14] = fmaf(d3.z, p, acc[14]);
        acc[15] = fmaf(d3.w, p, acc[15]);
    }
    __syncthreads();   // s_invZ ready

    const float scale = 0.3989422804014327f * inv_s;   // INV_SQRT_2PI / sigma_n
    #pragma unroll
    for (int r = 0; r < G; ++r) {
        int br = b0 + r;
        if (br < Bn) out[br * NB + tid] = acc[r] * (s_invZ[r] * scale);
    }
}

extern "C" void kernel_launch(void* const* d_in, const int* in_sizes, int n_in,
                              void* d_out, int out_size, void* d_ws, size_t ws_size,
                              hipStream_t stream) {
    const float* theta = (const float*)d_in[0];
    const float* mu    = (const float*)d_in[1];
    const float* sigma = (const float*)d_in[2];
    float* outp = (float*)d_out;

    int Bn = in_sizes[0] / TC;                 // 4096
    int grid = (Bn + G - 1) / G;               // 256 blocks -> 1 per CU
    fused_kernel<<<grid, BT, 0, stream>>>(theta, mu, sigma, outp, Bn);
}